// Round 10
// baseline (341.363 us; speedup 1.0000x reference)
//
#include <hip/hip_runtime.h>
#include <stdint.h>

#define T_TOK 2048
#define HDIM  2048
#define FDIM  1024
#define NEXP  8

#define BM   128
#define BK   64
#define NTHR 256
#define MT_MAX 16                 // 2048 / BM
#define BN1  64
#define BN2  64
#define NT1 (FDIM / BN1)          // 16
#define NT2 (HDIM / BN2)          // 32
#define NK1 (HDIM / BK)           // 32
#define NK2 (FDIM / BK)           // 16
#define GRID1 (NEXP * MT_MAX * NT1)   // 2048
#define GRID2 (NEXP * MT_MAX * NT2)   // 4096
#define BSTRIDE 34                // u32 row stride for B LDS (k-pairs)

typedef unsigned short u16;
typedef __attribute__((ext_vector_type(16))) float f32x16;
typedef __attribute__((ext_vector_type(8))) short bf16x8;

__device__ __forceinline__ u16 f2bf(float f) {
  uint32_t u = __float_as_uint(f);
  u += 0x7FFFu + ((u >> 16) & 1u);   // RNE
  return (u16)(u >> 16);
}

__device__ __forceinline__ uint32_t pack2(float lo, float hi) {
  return (uint32_t)f2bf(lo) | ((uint32_t)f2bf(hi) << 16);
}

__device__ __forceinline__ void glds16(const u16* src, u16* dst) {
  __builtin_amdgcn_global_load_lds(
      (const __attribute__((address_space(1))) uint32_t*)src,
      (__attribute__((address_space(3))) uint32_t*)dst, 16, 0, 0);
}

// read 8 bf16 (4 u32) from B LDS as two 8B-aligned uint2s
__device__ __forceinline__ bf16x8 bfrag(const uint32_t* base) {
  uint2 q0 = *(const uint2*)(base);
  uint2 q1 = *(const uint2*)(base + 2);
  union { uint4 u; bf16x8 b; } cv;
  cv.u = make_uint4(q0.x, q0.y, q1.x, q1.y);
  return cv.b;
}

// ---------------------------------------------------------------------------
// Routing (order-invariant y; see R2 notes).
// ---------------------------------------------------------------------------
__global__ void route1_kernel(const float* __restrict__ logits,
                              int* __restrict__ tok_e, float* __restrict__ tok_w,
                              int* __restrict__ counts) {
  __shared__ int lcnt[NEXP];
  const int tid = threadIdx.x;
  const int t = blockIdx.x * 256 + tid;
  if (tid < NEXP) lcnt[tid] = 0;
  __syncthreads();
  float l[NEXP];
#pragma unroll
  for (int e = 0; e < NEXP; ++e) l[e] = logits[t * NEXP + e];
  float m = l[0];
#pragma unroll
  for (int e = 1; e < NEXP; ++e) m = fmaxf(m, l[e]);
  float p[NEXP]; float s = 0.f;
#pragma unroll
  for (int e = 0; e < NEXP; ++e) { p[e] = __expf(l[e] - m); s += p[e]; }
  float inv = 1.f / s;
  int i0 = 0; float p0 = p[0];
#pragma unroll
  for (int e = 1; e < NEXP; ++e) if (p[e] > p0) { p0 = p[e]; i0 = e; }
  int i1 = -1; float p1 = -1.f;
#pragma unroll
  for (int e = 0; e < NEXP; ++e) if (e != i0 && p[e] > p1) { p1 = p[e]; i1 = e; }
  tok_e[t] = i0 | (i1 << 8);
  tok_w[t * 2]     = p0 * inv;
  tok_w[t * 2 + 1] = p1 * inv;
  atomicAdd(&lcnt[i0], 1);
  atomicAdd(&lcnt[i1], 1);
  __syncthreads();
  if (tid < NEXP) atomicAdd(&counts[tid], lcnt[tid]);
}

__global__ void route2_kernel(const int* __restrict__ counts,
                              int* __restrict__ offsets, int* __restrict__ cursor) {
  if (threadIdx.x == 0) {
    int s = 0;
    for (int e = 0; e < NEXP; ++e) { offsets[e] = s; cursor[e] = s; s += counts[e]; }
    offsets[NEXP] = s;
  }
}

__global__ void route3_kernel(const int* __restrict__ tok_e, const float* __restrict__ tok_w,
                              int* __restrict__ cursor,
                              int* __restrict__ token_list, float* __restrict__ slot_w) {
  __shared__ int lcnt[NEXP], lbase[NEXP];
  const int tid = threadIdx.x;
  const int t = blockIdx.x * 256 + tid;
  if (tid < NEXP) lcnt[tid] = 0;
  __syncthreads();
  int ee = tok_e[t];
  int e0 = ee & 255, e1 = ee >> 8;
  int li0 = atomicAdd(&lcnt[e0], 1);
  int li1 = atomicAdd(&lcnt[e1], 1);
  __syncthreads();
  if (tid < NEXP) lbase[tid] = atomicAdd(&cursor[tid], lcnt[tid]);
  __syncthreads();
  int s0 = lbase[e0] + li0;
  int s1 = lbase[e1] + li1;
  token_list[s0] = t; slot_w[s0] = tok_w[t * 2];
  token_list[s1] = t; slot_w[s1] = tok_w[t * 2 + 1];
}

__global__ void convert_x_kernel(const float4* __restrict__ x, ushort4* __restrict__ xb) {
  int i = blockIdx.x * 256 + threadIdx.x;
  float4 v = x[i];
  ushort4 o;
  o.x = f2bf(v.x); o.y = f2bf(v.y); o.z = f2bf(v.z); o.w = f2bf(v.w);
  xb[i] = o;
}

// ---------------------------------------------------------------------------
// GEMM1-fused: act[slot,f] = silu(x@w1)*(x@w3)*combine_w  (bf16 out)
// B staged straight from fp32 w1/w3 [H][F]: per K-step, thread reads 2 rows x
// 8 cols (4 coalesced float4), packs k-pairs -> u32 LDS [n][34] (transposed).
// Loads(t+1) reg-issued right after top barrier (no LDS hazard); A via glds16
// issued post-frag-reads (R5 proven). 32 MFMA (32x32x16) per K-step per wave.
// ---------------------------------------------------------------------------
__global__ __launch_bounds__(NTHR, 3)
void gemm1_kernel(const u16* __restrict__ Xb,
                  const float* __restrict__ w1,   // [E][H][F] fp32
                  const float* __restrict__ w3,
                  const int* __restrict__ token_list,
                  const float* __restrict__ slot_w,
                  const int* __restrict__ counts,
                  const int* __restrict__ offsets,
                  u16* __restrict__ act) {
  const int bid = blockIdx.x;
  const int e  = bid >> 8;
  const int mt = (bid >> 4) & 15;
  const int nt = bid & 15;     // nt fastest: same-B-panel blocks 16 apart -> same XCD
  const int cnt = counts[e];
  if (mt * BM >= cnt) return;
  const int off = offsets[e];
  const int tid  = threadIdx.x;
  const int lane = tid & 63;
  const int wid  = tid >> 6;
  const int wr = wid >> 1;
  const int wc = wid & 1;

  __shared__ u16 A_lds[BM * BK];              // 16 KB, granule^(row&7)
  __shared__ uint32_t B1u[BN1 * BSTRIDE];     // 8.5 KB: [n][k-pair], stride 34
  __shared__ uint32_t B3u[BN1 * BSTRIDE];

  const u16* a_src[4];
#pragma unroll
  for (int i = 0; i < 4; ++i) {
    int row = (wid * 4 + i) * 8 + (lane >> 3);
    int mg = mt * BM + row;
    int mc = (mg < cnt) ? mg : (cnt - 1);
    int tok = token_list[off + mc];
    a_src[i] = Xb + (size_t)tok * HDIM + (((lane & 7) ^ (row & 7)) * 8);
  }

  // B staging: thread (kp = tid>>3 in 0..31 -> rows 2kp,2kp+1; cg = tid&7 ->
  // cols cg*8..+8).  8-lane groups read 256B contiguous per row (coalesced).
  const int kp = tid >> 3;
  const int cg = tid & 7;
  const float* p1 = w1 + (size_t)e * HDIM * FDIM + (size_t)(2 * kp) * FDIM + nt * BN1 + cg * 8;
  const float* p3 = w3 + (size_t)e * HDIM * FDIM + (size_t)(2 * kp) * FDIM + nt * BN1 + cg * 8;

  f32x16 accg[2] = {};
  f32x16 accu[2] = {};

  float4 x1a, x1b, x1c, x1d, x3a, x3b, x3c, x3d;
#define LOADB(ks)                                                      \
  { const float* q1 = p1 + (size_t)(ks) * FDIM;                        \
    const float* q3 = p3 + (size_t)(ks) * FDIM;                        \
    x1a = *(const float4*)(q1);        x1b = *(const float4*)(q1 + 4); \
    x1c = *(const float4*)(q1 + FDIM); x1d = *(const float4*)(q1 + FDIM + 4); \
    x3a = *(const float4*)(q3);        x3b = *(const float4*)(q3 + 4); \
    x3c = *(const float4*)(q3 + FDIM); x3d = *(const float4*)(q3 + FDIM + 4); }

  // prologue: A glds(0) + B loads(0)
#pragma unroll
  for (int i = 0; i < 4; ++i) glds16(a_src[i], &A_lds[(wid * 4 + i) * 512]);
  LOADB(0);

#pragma unroll 1
  for (int t = 0; t < NK1; ++t) {
    // pack B(t) -> LDS (u32 k-pairs, lo = even k)
    {
      uint32_t* d1 = &B1u[(cg * 8) * BSTRIDE + kp];
      uint32_t* d3 = &B3u[(cg * 8) * BSTRIDE + kp];
      d1[0 * BSTRIDE] = pack2(x1a.x, x1c.x);
      d1[1 * BSTRIDE] = pack2(x1a.y, x1c.y);
      d1[2 * BSTRIDE] = pack2(x1a.z, x1c.z);
      d1[3 * BSTRIDE] = pack2(x1a.w, x1c.w);
      d1[4 * BSTRIDE] = pack2(x1b.x, x1d.x);
      d1[5 * BSTRIDE] = pack2(x1b.y, x1d.y);
      d1[6 * BSTRIDE] = pack2(x1b.z, x1d.z);
      d1[7 * BSTRIDE] = pack2(x1b.w, x1d.w);
      d3[0 * BSTRIDE] = pack2(x3a.x, x3c.x);
      d3[1 * BSTRIDE] = pack2(x3a.y, x3c.y);
      d3[2 * BSTRIDE] = pack2(x3a.z, x3c.z);
      d3[3 * BSTRIDE] = pack2(x3a.w, x3c.w);
      d3[4 * BSTRIDE] = pack2(x3b.x, x3d.x);
      d3[5 * BSTRIDE] = pack2(x3b.y, x3d.y);
      d3[6 * BSTRIDE] = pack2(x3b.z, x3d.z);
      d3[7 * BSTRIDE] = pack2(x3b.w, x3d.w);
    }
    __syncthreads();             // A glds(t) drained + B writes visible
    if (t + 1 < NK1) LOADB((t + 1) * BK);   // reg loads fly under reads+MFMA

    bf16x8 af[2][4], bg[4], bu[4];
#pragma unroll
    for (int m = 0; m < 2; ++m) {
      int R = wr * 64 + m * 32 + (lane & 31);
#pragma unroll
      for (int kk = 0; kk < 4; ++kk) {
        int gl = kk * 2 + (lane >> 5);
        af[m][kk] = *(const bf16x8*)&A_lds[R * BK + ((gl ^ (R & 7)) * 8)];
      }
    }
    {
      int n = wc * 32 + (lane & 31);
      const uint32_t* b1p = &B1u[n * BSTRIDE + (lane >> 5) * 4];
      const uint32_t* b3p = &B3u[n * BSTRIDE + (lane >> 5) * 4];
#pragma unroll
      for (int kk = 0; kk < 4; ++kk) {
        bg[kk] = bfrag(b1p + kk * 8);
        bu[kk] = bfrag(b3p + kk * 8);
      }
    }
    __syncthreads();             // all LDS reads done -> safe to overwrite
    if (t + 1 < NK1) {
      const int ks = (t + 1) * BK;
#pragma unroll
      for (int i = 0; i < 4; ++i) glds16(a_src[i] + ks, &A_lds[(wid * 4 + i) * 512]);
    }
    __builtin_amdgcn_s_setprio(1);
#pragma unroll
    for (int m = 0; m < 2; ++m)
#pragma unroll
      for (int kk = 0; kk < 4; ++kk) {
        accg[m] = __builtin_amdgcn_mfma_f32_32x32x16_bf16(af[m][kk], bg[kk], accg[m], 0, 0, 0);
        accu[m] = __builtin_amdgcn_mfma_f32_32x32x16_bf16(af[m][kk], bu[kk], accu[m], 0, 0, 0);
      }
    __builtin_amdgcn_s_setprio(0);
  }
#undef LOADB

  // epilogue. 32x32 C/D: col=lane&31, row=(reg&3)+8*(reg>>2)+4*(lane>>5)
  const int fcol = nt * BN1 + wc * 32 + (lane & 31);
#pragma unroll
  for (int m = 0; m < 2; ++m) {
    int base = mt * BM + wr * 64 + m * 32 + 4 * (lane >> 5);
#pragma unroll
    for (int reg = 0; reg < 16; ++reg) {
      int mg = base + (reg & 3) + 8 * (reg >> 2);
      if (mg < cnt) {
        int slot = off + mg;
        float wgt = slot_w[slot];
        float g = accg[m][reg];
        float u = accu[m][reg];
        float sv = g / (1.f + __expf(-g));
        act[(size_t)slot * FDIM + fcol] = f2bf(sv * u * wgt);
      }
    }
  }
}

// ---------------------------------------------------------------------------
// GEMM2-fused: y[token,h] += act[slot,:] @ w2[e]  (fp32 atomics)
// Same fused-B structure, single B matrix from w2 [F][H] fp32. BN=64,
// grid 4096 (max TLP), wave tile 64x32.
// ---------------------------------------------------------------------------
__global__ __launch_bounds__(NTHR, 3)
void gemm2_kernel(const u16* __restrict__ act,
                  const float* __restrict__ w2,   // [E][F][H] fp32
                  const int* __restrict__ token_list,
                  const int* __restrict__ counts,
                  const int* __restrict__ offsets,
                  float* __restrict__ y) {
  const int bid = blockIdx.x;
  const int e  = bid >> 9;
  const int mt = (bid >> 5) & 15;
  const int nt = bid & 31;
  const int cnt = counts[e];
  if (mt * BM >= cnt) return;
  const int off = offsets[e];
  const int tid  = threadIdx.x;
  const int lane = tid & 63;
  const int wid  = tid >> 6;
  const int wr = wid >> 1;
  const int wc = wid & 1;

  __shared__ u16 A_lds[BM * BK];            // 16 KB
  __shared__ uint32_t Bu[BN2 * BSTRIDE];    // 8.5 KB

  const u16* a_src[4];
#pragma unroll
  for (int i = 0; i < 4; ++i) {
    int row = (wid * 4 + i) * 8 + (lane >> 3);
    int mg = mt * BM + row;
    int mc = (mg < cnt) ? mg : (cnt - 1);
    a_src[i] = act + (size_t)(off + mc) * FDIM + (((lane & 7) ^ (row & 7)) * 8);
  }
  const int kp = tid >> 3;
  const int cg = tid & 7;
  const float* p2 = w2 + (size_t)e * FDIM * HDIM + (size_t)(2 * kp) * HDIM + nt * BN2 + cg * 8;

  f32x16 acc[2] = {};

  float4 xa, xb, xc, xd;
#define LOADB2(ks)                                                     \
  { const float* q = p2 + (size_t)(ks) * HDIM;                         \
    xa = *(const float4*)(q);        xb = *(const float4*)(q + 4);     \
    xc = *(const float4*)(q + HDIM); xd = *(const float4*)(q + HDIM + 4); }

#pragma unroll
  for (int i = 0; i < 4; ++i) glds16(a_src[i], &A_lds[(wid * 4 + i) * 512]);
  LOADB2(0);

#pragma unroll 1
  for (int t = 0; t < NK2; ++t) {
    {
      uint32_t* d = &Bu[(cg * 8) * BSTRIDE + kp];
      d[0 * BSTRIDE] = pack2(xa.x, xc.x);
      d[1 * BSTRIDE] = pack2(xa.y, xc.y);
      d[2 * BSTRIDE] = pack2(xa.z, xc.z);
      d[3 * BSTRIDE] = pack2(xa.w, xc.w);
      d[4 * BSTRIDE] = pack2(xb.x, xd.x);
      d[5 * BSTRIDE] = pack2(xb.y, xd.y);
      d[6 * BSTRIDE] = pack2(xb.z, xd.z);
      d[7 * BSTRIDE] = pack2(xb.w, xd.w);
    }
    __syncthreads();
    if (t + 1 < NK2) LOADB2((t + 1) * BK);

    bf16x8 af[2][4], bb[4];
#pragma unroll
    for (int m = 0; m < 2; ++m) {
      int R = wr * 64 + m * 32 + (lane & 31);
#pragma unroll
      for (int kk = 0; kk < 4; ++kk) {
        int gl = kk * 2 + (lane >> 5);
        af[m][kk] = *(const bf16x8*)&A_lds[R * BK + ((gl ^ (R & 7)) * 8)];
      }
    }
    {
      int n = wc * 32 + (lane & 31);
      const uint32_t* bp = &Bu[n * BSTRIDE + (lane >> 5) * 4];
#pragma unroll
      for (int kk = 0; kk < 4; ++kk) bb[kk] = bfrag(bp + kk * 8);
    }
    __syncthreads();
    if (t + 1 < NK2) {
      const int ks = (t + 1) * BK;
#pragma unroll
      for (int i = 0; i < 4; ++i) glds16(a_src[i] + ks, &A_lds[(wid * 4 + i) * 512]);
    }
    __builtin_amdgcn_s_setprio(1);
#pragma unroll
    for (int m = 0; m < 2; ++m)
#pragma unroll
      for (int kk = 0; kk < 4; ++kk)
        acc[m] = __builtin_amdgcn_mfma_f32_32x32x16_bf16(af[m][kk], bb[kk], acc[m], 0, 0, 0);
    __builtin_amdgcn_s_setprio(0);
  }
#undef LOADB2

  const int hcol = nt * BN2 + wc * 32 + (lane & 31);
#pragma unroll
  for (int m = 0; m < 2; ++m) {
    int base = mt * BM + wr * 64 + m * 32 + 4 * (lane >> 5);
#pragma unroll
    for (int reg = 0; reg < 16; ++reg) {
      int mg = base + (reg & 3) + 8 * (reg >> 2);
      if (mg < cnt) {
        int slot = off + mg;
        int tok = token_list[slot];
        unsafeAtomicAdd(y + (size_t)tok * HDIM + hcol, acc[m][reg]);
      }
    }
  }
}

// ---------------------------------------------------------------------------
extern "C" void kernel_launch(void* const* d_in, const int* in_sizes, int n_in,
                              void* d_out, int out_size, void* d_ws, size_t ws_size,
                              hipStream_t stream) {
  (void)in_sizes; (void)n_in; (void)out_size; (void)ws_size;
  const float* hs     = (const float*)d_in[0];
  const float* logits = (const float*)d_in[1];
  const float* w1     = (const float*)d_in[2];
  const float* w3     = (const float*)d_in[3];
  const float* w2     = (const float*)d_in[4];
  float* y = (float*)d_out;

  uint8_t* ws = (uint8_t*)d_ws;
  int*   token_list = (int*)(ws);
  float* slot_w     = (float*)(ws + (16 << 10));
  int*   counts     = (int*)(ws + (32 << 10));
  int*   offsets    = (int*)(ws + (32 << 10) + 128);
  int*   cursor     = (int*)(ws + (32 << 10) + 256);
  int*   tok_e      = (int*)(ws + (33 << 10));
  float* tok_w      = (float*)(ws + (42 << 10));
  const size_t MB = 1 << 20;
  u16*   Xb  = (u16*)(ws + (64 << 10));                 // 8 MB
  u16*   act = (u16*)(ws + (64 << 10) + 8 * MB);        // 8 MB

  hipMemsetAsync(counts, 0, NEXP * sizeof(int), stream);
  route1_kernel<<<T_TOK / 256, 256, 0, stream>>>(logits, tok_e, tok_w, counts);
  route2_kernel<<<1, 64, 0, stream>>>(counts, offsets, cursor);
  route3_kernel<<<T_TOK / 256, 256, 0, stream>>>(tok_e, tok_w, cursor, token_list, slot_w);
  convert_x_kernel<<<(T_TOK * HDIM / 4) / 256, 256, 0, stream>>>((const float4*)hs, (ushort4*)Xb);
  hipMemsetAsync(d_out, 0, (size_t)T_TOK * HDIM * sizeof(float), stream);
  gemm1_kernel<<<GRID1, NTHR, 0, stream>>>(Xb, w1, w3, token_list, slot_w, counts, offsets, act);
  gemm2_kernel<<<GRID2, NTHR, 0, stream>>>(act, w2, token_list, counts, offsets, y);
}

// Round 11
// 182.008 us; speedup vs baseline: 1.8755x; 1.8755x over previous
//
#include <hip/hip_runtime.h>
#include <stdint.h>

#define T_TOK 2048
#define HDIM  2048
#define FDIM  1024
#define NEXP  8

#define BM   128
#define BK   64
#define NTHR 256
#define MT_MAX 16                 // 2048 / BM
#define BN1  64
#define BN2  128
#define NT1 (FDIM / BN1)          // 16
#define NT2 (HDIM / BN2)          // 16
#define NK1 (HDIM / BK)           // 32
#define NK2 (FDIM / BK)           // 16
#define GRID1 (NEXP * MT_MAX * NT1)   // 2048
#define GRID2 (NEXP * MT_MAX * NT2)   // 2048
#define TILE_E 4096               // elems per 64x64 bf16 tile (8 KB)

typedef unsigned short u16;
typedef __attribute__((ext_vector_type(16))) float f32x16;
typedef __attribute__((ext_vector_type(8))) short bf16x8;

__device__ __forceinline__ u16 f2bf(float f) {
  uint32_t u = __float_as_uint(f);
  u += 0x7FFFu + ((u >> 16) & 1u);   // RNE
  return (u16)(u >> 16);
}

__device__ __forceinline__ uint32_t pack2(float lo, float hi) {
  return (uint32_t)f2bf(lo) | ((uint32_t)f2bf(hi) << 16);
}

__device__ __forceinline__ void glds16(const u16* src, u16* dst) {
  __builtin_amdgcn_global_load_lds(
      (const __attribute__((address_space(1))) uint32_t*)src,
      (__attribute__((address_space(3))) uint32_t*)dst, 16, 0, 0);
}

// ---------------------------------------------------------------------------
// Routing (order-invariant y; see R2 notes).
// ---------------------------------------------------------------------------
__global__ void route1_kernel(const float* __restrict__ logits,
                              int* __restrict__ tok_e, float* __restrict__ tok_w,
                              int* __restrict__ counts) {
  __shared__ int lcnt[NEXP];
  const int tid = threadIdx.x;
  const int t = blockIdx.x * 256 + tid;
  if (tid < NEXP) lcnt[tid] = 0;
  __syncthreads();
  float l[NEXP];
#pragma unroll
  for (int e = 0; e < NEXP; ++e) l[e] = logits[t * NEXP + e];
  float m = l[0];
#pragma unroll
  for (int e = 1; e < NEXP; ++e) m = fmaxf(m, l[e]);
  float p[NEXP]; float s = 0.f;
#pragma unroll
  for (int e = 0; e < NEXP; ++e) { p[e] = __expf(l[e] - m); s += p[e]; }
  float inv = 1.f / s;
  int i0 = 0; float p0 = p[0];
#pragma unroll
  for (int e = 1; e < NEXP; ++e) if (p[e] > p0) { p0 = p[e]; i0 = e; }
  int i1 = -1; float p1 = -1.f;
#pragma unroll
  for (int e = 0; e < NEXP; ++e) if (e != i0 && p[e] > p1) { p1 = p[e]; i1 = e; }
  tok_e[t] = i0 | (i1 << 8);
  tok_w[t * 2]     = p0 * inv;
  tok_w[t * 2 + 1] = p1 * inv;
  atomicAdd(&lcnt[i0], 1);
  atomicAdd(&lcnt[i1], 1);
  __syncthreads();
  if (tid < NEXP) atomicAdd(&counts[tid], lcnt[tid]);
}

__global__ void route2_kernel(const int* __restrict__ counts,
                              int* __restrict__ offsets, int* __restrict__ cursor) {
  if (threadIdx.x == 0) {
    int s = 0;
    for (int e = 0; e < NEXP; ++e) { offsets[e] = s; cursor[e] = s; s += counts[e]; }
    offsets[NEXP] = s;
  }
}

__global__ void route3_kernel(const int* __restrict__ tok_e, const float* __restrict__ tok_w,
                              int* __restrict__ cursor,
                              int* __restrict__ token_list, float* __restrict__ slot_w) {
  __shared__ int lcnt[NEXP], lbase[NEXP];
  const int tid = threadIdx.x;
  const int t = blockIdx.x * 256 + tid;
  if (tid < NEXP) lcnt[tid] = 0;
  __syncthreads();
  int ee = tok_e[t];
  int e0 = ee & 255, e1 = ee >> 8;
  int li0 = atomicAdd(&lcnt[e0], 1);
  int li1 = atomicAdd(&lcnt[e1], 1);
  __syncthreads();
  if (tid < NEXP) lbase[tid] = atomicAdd(&cursor[tid], lcnt[tid]);
  __syncthreads();
  int s0 = lbase[e0] + li0;
  int s1 = lbase[e1] + li1;
  token_list[s0] = t; slot_w[s0] = tok_w[t * 2];
  token_list[s1] = t; slot_w[s1] = tok_w[t * 2 + 1];
}

__global__ void convert_x_kernel(const float4* __restrict__ x, ushort4* __restrict__ xb) {
  int i = blockIdx.x * 256 + threadIdx.x;
  float4 v = x[i];
  ushort4 o;
  o.x = f2bf(v.x); o.y = f2bf(v.y); o.z = f2bf(v.z); o.w = f2bf(v.w);
  xb[i] = o;
}

// ---------------------------------------------------------------------------
// Transpose+convert into TILED blobs: dst = [e][n-tile][k-tile][4096 elems],
// blob elem (n,k) at n*64 + (((k>>3)^(n&7))*8) + (k&7)  (gemm frag order,
// granule-XOR baked in). Block: 256(k) x 64(n) panel -> 4 k-tiles = 32 KB
// CONTIGUOUS write (fixes the 512B@4KB-stride write pattern of row-major dst).
// Reads coalesced (256 B/row). One barrier.
// ---------------------------------------------------------------------------
__global__ __launch_bounds__(256, 4)
void tconv_tiled_kernel(const float* __restrict__ w1, const float* __restrict__ w3,
                        const float* __restrict__ w2,
                        u16* __restrict__ w1b, u16* __restrict__ w3b, u16* __restrict__ w2b) {
  const int zb = blockIdx.y;
  const int which = zb >> 3;
  const int e = zb & 7;
  const int x = blockIdx.x;
  const float* src; u16* dstbase; int C, ct, ktg, NKT;
  if (which == 0)      { src = w1; dstbase = w1b; C = FDIM; ct = x & 15; ktg = x >> 4; NKT = 32; }
  else if (which == 1) { src = w3; dstbase = w3b; C = FDIM; ct = x & 15; ktg = x >> 4; NKT = 32; }
  else                 { src = w2; dstbase = w2b; C = HDIM; ct = x & 31; ktg = x >> 5; NKT = 16; }
  const size_t msz = (size_t)HDIM * FDIM;
  src += (size_t)e * msz;
  const int NTt = (which == 2) ? 32 : 16;
  u16* blob = dstbase + (((size_t)e * NTt + ct) * NKT + ktg * 4) * TILE_E;
  const int r0 = ktg * 256;     // k offset (src row)
  const int c0 = ct * 64;       // n offset (src col)

  __shared__ uint32_t T[4][64 * 33];   // 33 KB
  const int t = threadIdx.x;

  // phase 1: all 16 float4 loads up-front, cvt+pack -> LDS (u32 k-pairs)
  const int kp = t >> 3;        // row-pair 0..31 within tile
  const int cg = t & 7;         // col group of 8
  float4 a0[4], a1[4], b0[4], b1[4];
#pragma unroll
  for (int i = 0; i < 4; ++i) {
    const float* s0 = src + (size_t)(r0 + i * 64 + 2 * kp) * C + c0 + cg * 8;
    a0[i] = *(const float4*)(s0);
    a1[i] = *(const float4*)(s0 + 4);
    b0[i] = *(const float4*)(s0 + C);
    b1[i] = *(const float4*)(s0 + C + 4);
  }
#pragma unroll
  for (int i = 0; i < 4; ++i) {
    uint32_t* Ti = T[i];
    Ti[(cg * 8 + 0) * 33 + kp] = pack2(a0[i].x, b0[i].x);
    Ti[(cg * 8 + 1) * 33 + kp] = pack2(a0[i].y, b0[i].y);
    Ti[(cg * 8 + 2) * 33 + kp] = pack2(a0[i].z, b0[i].z);
    Ti[(cg * 8 + 3) * 33 + kp] = pack2(a0[i].w, b0[i].w);
    Ti[(cg * 8 + 4) * 33 + kp] = pack2(a1[i].x, b1[i].x);
    Ti[(cg * 8 + 5) * 33 + kp] = pack2(a1[i].y, b1[i].y);
    Ti[(cg * 8 + 6) * 33 + kp] = pack2(a1[i].z, b1[i].z);
    Ti[(cg * 8 + 7) * 33 + kp] = pack2(a1[i].w, b1[i].w);
  }
  __syncthreads();

  // phase 2: write blob in fragment order. u32 view: k-pair kp of row n at
  // n*32 + (((kp>>2)^(n&7))*4) + (kp&3). Per 4-thread group covers a full
  // 128B row; 4 tiles -> 32 KB contiguous per block.
  const int f  = t >> 2;        // n row 0..63
  const int kg = t & 3;
  const int swl = f & 7;
  uint32_t* bu = (uint32_t*)blob;
#pragma unroll
  for (int i = 0; i < 4; ++i) {
    const uint32_t* Ti = T[i] + f * 33 + kg * 8;
    uint4 q0 = {Ti[0], Ti[1], Ti[2], Ti[3]};
    uint4 q1 = {Ti[4], Ti[5], Ti[6], Ti[7]};
    uint32_t* br = bu + i * 2048 + f * 32;
    *(uint4*)(br + (((kg * 2) ^ swl) * 4))     = q0;
    *(uint4*)(br + (((kg * 2 + 1) ^ swl) * 4)) = q1;
  }
}

// ---------------------------------------------------------------------------
// GEMM1 (R9-proven schedule): BM=128 BN=64 BK=64, 4 waves, wave tile 64x32
// dual-B, single-buffer, reads -> barrier -> stage-issue -> MFMA.
// B now staged from tiled blobs: pure sequential 8 KB stream per K-step.
// ---------------------------------------------------------------------------
__global__ __launch_bounds__(NTHR, 3)
void gemm1_kernel(const u16* __restrict__ Xb,
                  const u16* __restrict__ w1b,   // tiled [e][nt16][kt32][4096]
                  const u16* __restrict__ w3b,
                  const int* __restrict__ token_list,
                  const float* __restrict__ slot_w,
                  const int* __restrict__ counts,
                  const int* __restrict__ offsets,
                  u16* __restrict__ act) {
  const int bid = blockIdx.x;
  const int e  = bid >> 8;
  const int mt = (bid >> 4) & 15;
  const int nt = bid & 15;
  const int cnt = counts[e];
  if (mt * BM >= cnt) return;
  const int off = offsets[e];
  const int tid  = threadIdx.x;
  const int lane = tid & 63;
  const int wid  = tid >> 6;
  const int wr = wid >> 1;       // 0..1 (m half)
  const int wc = wid & 1;        // 0..1 (n half)

  __shared__ u16 A_lds[BM * BK];     // 16 KB  [row][64], granule^(row&7)
  __shared__ u16 B1_lds[BN1 * BK];   // 8 KB (fragment order from blob)
  __shared__ u16 B3_lds[BN1 * BK];   // 8 KB

  const u16* a_src[4];
#pragma unroll
  for (int i = 0; i < 4; ++i) {
    int row = (wid * 4 + i) * 8 + (lane >> 3);
    int mg = mt * BM + row;
    int mc = (mg < cnt) ? mg : (cnt - 1);
    int tok = token_list[off + mc];
    a_src[i] = Xb + (size_t)tok * HDIM + (((lane & 7) ^ (row & 7)) * 8);
  }
  const u16* b1_src[2];
  const u16* b3_src[2];
  {
    size_t tbase = ((size_t)(e * 16 + nt) * 32) * TILE_E;
#pragma unroll
    for (int i = 0; i < 2; ++i) {
      int c = wid * 2 + i;
      b1_src[i] = w1b + tbase + c * 512 + lane * 8;
      b3_src[i] = w3b + tbase + c * 512 + lane * 8;
    }
  }

  f32x16 accg[2] = {};
  f32x16 accu[2] = {};

#pragma unroll
  for (int i = 0; i < 4; ++i) glds16(a_src[i], &A_lds[(wid * 4 + i) * 512]);
#pragma unroll
  for (int i = 0; i < 2; ++i) {
    glds16(b1_src[i], &B1_lds[(wid * 2 + i) * 512]);
    glds16(b3_src[i], &B3_lds[(wid * 2 + i) * 512]);
  }

#pragma unroll 1
  for (int t = 0; t < NK1; ++t) {
    __syncthreads();   // stage(t) drained -> tile t visible
    bf16x8 af[2][4], bg[4], bu[4];
#pragma unroll
    for (int m = 0; m < 2; ++m) {
      int R = wr * 64 + m * 32 + (lane & 31);
#pragma unroll
      for (int kk = 0; kk < 4; ++kk) {
        int gl = kk * 2 + (lane >> 5);
        af[m][kk] = *(const bf16x8*)&A_lds[R * BK + ((gl ^ (R & 7)) * 8)];
      }
    }
    {
      int R = wc * 32 + (lane & 31);
#pragma unroll
      for (int kk = 0; kk < 4; ++kk) {
        int gl = kk * 2 + (lane >> 5);
        int pos = R * BK + ((gl ^ (R & 7)) * 8);
        bg[kk] = *(const bf16x8*)&B1_lds[pos];
        bu[kk] = *(const bf16x8*)&B3_lds[pos];
      }
    }
    __syncthreads();   // all reads complete -> safe to overwrite
    if (t + 1 < NK1) { // in flight across MFMA phase; drained at next top barrier
      const size_t ks = (size_t)(t + 1) * BK;            // A: row-major k advance
      const size_t kb = (size_t)(t + 1) * TILE_E;        // B: next 8KB tile
#pragma unroll
      for (int i = 0; i < 4; ++i) glds16(a_src[i] + ks, &A_lds[(wid * 4 + i) * 512]);
#pragma unroll
      for (int i = 0; i < 2; ++i) {
        glds16(b1_src[i] + kb, &B1_lds[(wid * 2 + i) * 512]);
        glds16(b3_src[i] + kb, &B3_lds[(wid * 2 + i) * 512]);
      }
    }
#pragma unroll
    for (int m = 0; m < 2; ++m)
#pragma unroll
      for (int kk = 0; kk < 4; ++kk) {
        accg[m] = __builtin_amdgcn_mfma_f32_32x32x16_bf16(af[m][kk], bg[kk], accg[m], 0, 0, 0);
        accu[m] = __builtin_amdgcn_mfma_f32_32x32x16_bf16(af[m][kk], bu[kk], accu[m], 0, 0, 0);
      }
  }

  // epilogue. 32x32 C/D: col=lane&31, row=(reg&3)+8*(reg>>2)+4*(lane>>5)
  const int fcol = nt * BN1 + wc * 32 + (lane & 31);
#pragma unroll
  for (int m = 0; m < 2; ++m) {
    int base = mt * BM + wr * 64 + m * 32 + 4 * (lane >> 5);
#pragma unroll
    for (int reg = 0; reg < 16; ++reg) {
      int mg = base + (reg & 3) + 8 * (reg >> 2);
      if (mg < cnt) {
        int slot = off + mg;
        float wgt = slot_w[slot];
        float g = accg[m][reg];
        float u = accu[m][reg];
        float sv = g / (1.f + __expf(-g));
        act[(size_t)slot * FDIM + fcol] = f2bf(sv * u * wgt);
      }
    }
  }
}

// ---------------------------------------------------------------------------
// GEMM2: y[token,h] += act[slot,:] @ w2[e] (tiled blob). BM=128 BN=128 BK=64,
// wave tile 64x64, 16 b128 reads : 16 MFMA. Same proven schedule.
// ---------------------------------------------------------------------------
__global__ __launch_bounds__(NTHR, 3)
void gemm2_kernel(const u16* __restrict__ act,
                  const u16* __restrict__ w2b,   // tiled [e][nt32][kt16][4096]
                  const int* __restrict__ token_list,
                  const int* __restrict__ counts,
                  const int* __restrict__ offsets,
                  float* __restrict__ y) {
  const int bid = blockIdx.x;
  const int e  = bid >> 8;
  const int mt = (bid >> 4) & 15;
  const int nt = bid & 15;
  const int cnt = counts[e];
  if (mt * BM >= cnt) return;
  const int off = offsets[e];
  const int tid  = threadIdx.x;
  const int lane = tid & 63;
  const int wid  = tid >> 6;
  const int wr = wid >> 1;
  const int wc = wid & 1;

  __shared__ u16 A_lds[BM * BK];     // 16 KB
  __shared__ u16 B_lds[BN2 * BK];    // 16 KB

  const u16* a_src[4];
  const u16* b_src[4];
#pragma unroll
  for (int i = 0; i < 4; ++i) {
    int row = (wid * 4 + i) * 8 + (lane >> 3);
    int mg = mt * BM + row;
    int mc = (mg < cnt) ? mg : (cnt - 1);
    a_src[i] = act + (size_t)(off + mc) * FDIM + (((lane & 7) ^ (row & 7)) * 8);
    int c = wid * 4 + i;
    size_t tbase = ((size_t)(e * 32 + nt * 2 + (c >> 3)) * 16) * TILE_E;
    b_src[i] = w2b + tbase + (c & 7) * 512 + lane * 8;
  }

  f32x16 acc[2][2] = {};

#pragma unroll
  for (int i = 0; i < 4; ++i) {
    glds16(a_src[i], &A_lds[(wid * 4 + i) * 512]);
    glds16(b_src[i], &B_lds[(wid * 4 + i) * 512]);
  }

#pragma unroll 1
  for (int t = 0; t < NK2; ++t) {
    __syncthreads();
    bf16x8 af[2][4], bb[2][4];
#pragma unroll
    for (int m = 0; m < 2; ++m) {
      int R = wr * 64 + m * 32 + (lane & 31);
#pragma unroll
      for (int kk = 0; kk < 4; ++kk) {
        int gl = kk * 2 + (lane >> 5);
        af[m][kk] = *(const bf16x8*)&A_lds[R * BK + ((gl ^ (R & 7)) * 8)];
      }
    }
#pragma unroll
    for (int n = 0; n < 2; ++n) {
      int R = wc * 64 + n * 32 + (lane & 31);
#pragma unroll
      for (int kk = 0; kk < 4; ++kk) {
        int gl = kk * 2 + (lane >> 5);
        bb[n][kk] = *(const bf16x8*)&B_lds[R * BK + ((gl ^ (R & 7)) * 8)];
      }
    }
    __syncthreads();
    if (t + 1 < NK2) {
      const size_t ks = (size_t)(t + 1) * BK;
      const size_t kb = (size_t)(t + 1) * TILE_E;
#pragma unroll
      for (int i = 0; i < 4; ++i) {
        glds16(a_src[i] + ks, &A_lds[(wid * 4 + i) * 512]);
        glds16(b_src[i] + kb, &B_lds[(wid * 4 + i) * 512]);
      }
    }
#pragma unroll
    for (int kk = 0; kk < 4; ++kk)
#pragma unroll
      for (int m = 0; m < 2; ++m)
#pragma unroll
        for (int n = 0; n < 2; ++n)
          acc[m][n] = __builtin_amdgcn_mfma_f32_32x32x16_bf16(af[m][kk], bb[n][kk], acc[m][n], 0, 0, 0);
  }

#pragma unroll
  for (int m = 0; m < 2; ++m) {
    int base = mt * BM + wr * 64 + m * 32 + 4 * (lane >> 5);
#pragma unroll
    for (int reg = 0; reg < 16; ++reg) {
      int mg = base + (reg & 3) + 8 * (reg >> 2);
      if (mg < cnt) {
        int slot = off + mg;
        int tok = token_list[slot];
#pragma unroll
        for (int n = 0; n < 2; ++n) {
          int hcol = nt * BN2 + wc * 64 + n * 32 + (lane & 31);
          unsafeAtomicAdd(y + (size_t)tok * HDIM + hcol, acc[m][n][reg]);
        }
      }
    }
  }
}

// ---------------------------------------------------------------------------
extern "C" void kernel_launch(void* const* d_in, const int* in_sizes, int n_in,
                              void* d_out, int out_size, void* d_ws, size_t ws_size,
                              hipStream_t stream) {
  (void)in_sizes; (void)n_in; (void)out_size; (void)ws_size;
  const float* hs     = (const float*)d_in[0];
  const float* logits = (const float*)d_in[1];
  const float* w1     = (const float*)d_in[2];
  const float* w3     = (const float*)d_in[3];
  const float* w2     = (const float*)d_in[4];
  float* y = (float*)d_out;

  uint8_t* ws = (uint8_t*)d_ws;
  int*   token_list = (int*)(ws);
  float* slot_w     = (float*)(ws + (16 << 10));
  int*   counts     = (int*)(ws + (32 << 10));
  int*   offsets    = (int*)(ws + (32 << 10) + 128);
  int*   cursor     = (int*)(ws + (32 << 10) + 256);
  int*   tok_e      = (int*)(ws + (33 << 10));
  float* tok_w      = (float*)(ws + (42 << 10));
  const size_t MB = 1 << 20;
  u16*   Xb  = (u16*)(ws + (64 << 10));                 // 8 MB
  u16*   act = (u16*)(ws + (64 << 10) + 8 * MB);        // 8 MB
  u16*   w1b = (u16*)(ws + (64 << 10) + 16 * MB);       // 32 MB tiled
  u16*   w3b = (u16*)(ws + (64 << 10) + 48 * MB);       // 32 MB tiled
  u16*   w2b = (u16*)(ws + (64 << 10) + 80 * MB);       // 32 MB tiled

  hipMemsetAsync(counts, 0, NEXP * sizeof(int), stream);
  route1_kernel<<<T_TOK / 256, 256, 0, stream>>>(logits, tok_e, tok_w, counts);
  route2_kernel<<<1, 64, 0, stream>>>(counts, offsets, cursor);
  route3_kernel<<<T_TOK / 256, 256, 0, stream>>>(tok_e, tok_w, cursor, token_list, slot_w);
  convert_x_kernel<<<(T_TOK * HDIM / 4) / 256, 256, 0, stream>>>((const float4*)hs, (ushort4*)Xb);
  tconv_tiled_kernel<<<dim3(128, 24), 256, 0, stream>>>(w1, w3, w2, w1b, w3b, w2b);
  hipMemsetAsync(d_out, 0, (size_t)T_TOK * HDIM * sizeof(float), stream);
  gemm1_kernel<<<GRID1, NTHR, 0, stream>>>(Xb, w1b, w3b, token_list, slot_w, counts, offsets, act);
  gemm2_kernel<<<GRID2, NTHR, 0, stream>>>(act, w2b, token_list, counts, offsets, y);
}

// Round 12
// 181.880 us; speedup vs baseline: 1.8769x; 1.0007x over previous
//
#include <hip/hip_runtime.h>
#include <stdint.h>

#define T_TOK 2048
#define HDIM  2048
#define FDIM  1024
#define NEXP  8

#define BM   128
#define BK   64
#define NTHR 256
#define MT_MAX 16                 // 2048 / BM
#define BN1  64
#define BN2  128
#define NT1 (FDIM / BN1)          // 16
#define NT2 (HDIM / BN2)          // 16
#define NK1 (HDIM / BK)           // 32
#define NK2 (FDIM / BK)           // 16
#define GRID2K (NEXP * MT_MAX * NT2)  // 2048 (gemm2)
#define TILE_E 4096               // elems per 64x64 bf16 tile (8 KB)
#define SMEM_BYTES 36864

typedef unsigned short u16;
typedef __attribute__((ext_vector_type(16))) float f32x16;
typedef __attribute__((ext_vector_type(8))) short bf16x8;

__device__ __forceinline__ u16 f2bf(float f) {
  uint32_t u = __float_as_uint(f);
  u += 0x7FFFu + ((u >> 16) & 1u);   // RNE
  return (u16)(u >> 16);
}

__device__ __forceinline__ uint32_t pack2(float lo, float hi) {
  return (uint32_t)f2bf(lo) | ((uint32_t)f2bf(hi) << 16);
}

__device__ __forceinline__ void glds16(const u16* src, u16* dst) {
  __builtin_amdgcn_global_load_lds(
      (const __attribute__((address_space(1))) uint32_t*)src,
      (__attribute__((address_space(3))) uint32_t*)dst, 16, 0, 0);
}

// ---------------------------------------------------------------------------
// Routing (order-invariant y; see R2 notes).
// ---------------------------------------------------------------------------
__global__ void route1_kernel(const float* __restrict__ logits,
                              int* __restrict__ tok_e, float* __restrict__ tok_w,
                              int* __restrict__ counts) {
  __shared__ int lcnt[NEXP];
  const int tid = threadIdx.x;
  const int t = blockIdx.x * 256 + tid;
  if (tid < NEXP) lcnt[tid] = 0;
  __syncthreads();
  float l[NEXP];
#pragma unroll
  for (int e = 0; e < NEXP; ++e) l[e] = logits[t * NEXP + e];
  float m = l[0];
#pragma unroll
  for (int e = 1; e < NEXP; ++e) m = fmaxf(m, l[e]);
  float p[NEXP]; float s = 0.f;
#pragma unroll
  for (int e = 0; e < NEXP; ++e) { p[e] = __expf(l[e] - m); s += p[e]; }
  float inv = 1.f / s;
  int i0 = 0; float p0 = p[0];
#pragma unroll
  for (int e = 1; e < NEXP; ++e) if (p[e] > p0) { p0 = p[e]; i0 = e; }
  int i1 = -1; float p1 = -1.f;
#pragma unroll
  for (int e = 0; e < NEXP; ++e) if (e != i0 && p[e] > p1) { p1 = p[e]; i1 = e; }
  tok_e[t] = i0 | (i1 << 8);
  tok_w[t * 2]     = p0 * inv;
  tok_w[t * 2 + 1] = p1 * inv;
  atomicAdd(&lcnt[i0], 1);
  atomicAdd(&lcnt[i1], 1);
  __syncthreads();
  if (tid < NEXP) atomicAdd(&counts[tid], lcnt[tid]);
}

__global__ void route2_kernel(const int* __restrict__ counts,
                              int* __restrict__ offsets, int* __restrict__ cursor) {
  if (threadIdx.x == 0) {
    int s = 0;
    for (int e = 0; e < NEXP; ++e) { offsets[e] = s; cursor[e] = s; s += counts[e]; }
    offsets[NEXP] = s;
  }
}

__global__ void route3_kernel(const int* __restrict__ tok_e, const float* __restrict__ tok_w,
                              int* __restrict__ cursor,
                              int* __restrict__ token_list, float* __restrict__ slot_w) {
  __shared__ int lcnt[NEXP], lbase[NEXP];
  const int tid = threadIdx.x;
  const int t = blockIdx.x * 256 + tid;
  if (tid < NEXP) lcnt[tid] = 0;
  __syncthreads();
  int ee = tok_e[t];
  int e0 = ee & 255, e1 = ee >> 8;
  int li0 = atomicAdd(&lcnt[e0], 1);
  int li1 = atomicAdd(&lcnt[e1], 1);
  __syncthreads();
  if (tid < NEXP) lbase[tid] = atomicAdd(&cursor[tid], lcnt[tid]);
  __syncthreads();
  int s0 = lbase[e0] + li0;
  int s1 = lbase[e1] + li1;
  token_list[s0] = t; slot_w[s0] = tok_w[t * 2];
  token_list[s1] = t; slot_w[s1] = tok_w[t * 2 + 1];
}

// ---------------------------------------------------------------------------
// Weight conversion block: LINEAR-READ variant. Reads 16 consecutive rows
// (r0..r0+15) x 1024 cols of fp32 src = 64 KB fully sequential. Writes the
// (kq = (r0>>4)&3) sub-block of 16 destination tiles, each a CONTIGUOUS 2 KB
// run. Blob intra-tile order: [kq4][n64][k16], with 8-elem halves swapped by
// s(n) = (n>>2)&1 (matches gemm frag-read swizzle).
// ---------------------------------------------------------------------------
__device__ __forceinline__ void wconv_block(const float* __restrict__ src,
                                            u16* __restrict__ dstb,
                                            int C, int NT, int NKT,
                                            int e, int r0, int c0, uint32_t* L) {
  const int t = threadIdx.x;
  const int p  = t >> 5;        // row-pair 0..7
  const int ln = t & 31;
  const float* row0 = src + (size_t)(r0 + 2 * p) * C + c0;
  const float* row1 = row0 + C;
  float4 f0[8], f1[8];
#pragma unroll
  for (int j = 0; j < 8; ++j) f0[j] = *(const float4*)(row0 + j * 128 + ln * 4);
#pragma unroll
  for (int j = 0; j < 8; ++j) f1[j] = *(const float4*)(row1 + j * 128 + ln * 4);
#pragma unroll
  for (int j = 0; j < 8; ++j) {
    int n = j * 128 + ln * 4;
    L[(n + 0) * 9 + p] = pack2(f0[j].x, f1[j].x);
    L[(n + 1) * 9 + p] = pack2(f0[j].y, f1[j].y);
    L[(n + 2) * 9 + p] = pack2(f0[j].z, f1[j].z);
    L[(n + 3) * 9 + p] = pack2(f0[j].w, f1[j].w);
  }
  __syncthreads();
  const int kt = r0 >> 6, kq = (r0 >> 4) & 3;
#pragma unroll
  for (int i = 0; i < 4; ++i) {
    int n = t * 4 + i;
    const uint32_t* a = &L[n * 9];
    uint4 lo = {a[0], a[1], a[2], a[3]};   // k 0..7 of this kq
    uint4 hi = {a[4], a[5], a[6], a[7]};   // k 8..15
    int ng = c0 + n;
    int s = (n >> 2) & 1;
    u16* tb = dstb + (((size_t)e * NT + (ng >> 6)) * NKT + kt) * TILE_E
                   + kq * 1024 + (n & 63) * 16;
    *(uint4*)(tb + s * 8)       = lo;
    *(uint4*)(tb + (s ^ 1) * 8) = hi;
  }
}

// ---------------------------------------------------------------------------
// MEGA1: bid<2048: w1/w3 conversion; 2048..2304: x fp32->bf16; 2304..2560:
// y zero-fill. All independent; fills the machine instead of serializing.
// ---------------------------------------------------------------------------
__global__ __launch_bounds__(256, 3)
void mega1_kernel(const float* __restrict__ w1, const float* __restrict__ w3,
                  u16* __restrict__ w1b, u16* __restrict__ w3b,
                  const float4* __restrict__ x, ushort4* __restrict__ xb,
                  float4* __restrict__ y4) {
  __shared__ __align__(16) uint8_t smem[SMEM_BYTES];
  const int bid = blockIdx.x;
  const int t = threadIdx.x;
  if (bid < 2048) {
    const int m = bid >> 10;
    const int r = bid & 1023;
    const int e = r >> 7;
    const int g = r & 127;
    const size_t msz = (size_t)HDIM * FDIM;
    wconv_block((m ? w3 : w1) + (size_t)e * msz, m ? w3b : w1b,
                FDIM, 16, 32, e, g * 16, 0, (uint32_t*)smem);
  } else if (bid < 2304) {
    int i = (bid - 2048) * 256 + t;
#pragma unroll
    for (int r = 0; r < 16; ++r, i += 65536) {
      float4 v = x[i];
      ushort4 o;
      o.x = f2bf(v.x); o.y = f2bf(v.y); o.z = f2bf(v.z); o.w = f2bf(v.w);
      xb[i] = o;
    }
  } else {
    int i = (bid - 2304) * 256 + t;
    float4 z = {0.f, 0.f, 0.f, 0.f};
#pragma unroll
    for (int r = 0; r < 16; ++r, i += 65536) y4[i] = z;
  }
}

// ---------------------------------------------------------------------------
// MEGA2: bid<1024: w2 conversion (independent of gemm1 -> runs concurrently);
// bid>=1024: gemm1 (R9/R11-proven schedule, new B-frag formula).
// ---------------------------------------------------------------------------
__global__ __launch_bounds__(256, 3)
void mega2_kernel(const float* __restrict__ w2, u16* __restrict__ w2b,
                  const u16* __restrict__ Xb,
                  const u16* __restrict__ w1b, const u16* __restrict__ w3b,
                  const int* __restrict__ token_list,
                  const float* __restrict__ slot_w,
                  const int* __restrict__ counts,
                  const int* __restrict__ offsets,
                  u16* __restrict__ act) {
  __shared__ __align__(16) uint8_t smem[SMEM_BYTES];
  const int bid = blockIdx.x;
  if (bid < 1024) {
    const int e = bid >> 7;
    const int r = bid & 127;
    const int g = r & 63;
    const int half = r >> 6;
    wconv_block(w2 + (size_t)e * HDIM * FDIM, w2b,
                HDIM, 32, 16, e, g * 16, half * 1024, (uint32_t*)smem);
    return;
  }
  const int gb = bid - 1024;
  const int e  = gb >> 8;
  const int mt = (gb >> 4) & 15;
  const int nt = gb & 15;
  const int cnt = counts[e];
  if (mt * BM >= cnt) return;
  const int off = offsets[e];
  const int tid  = threadIdx.x;
  const int lane = tid & 63;
  const int wid  = tid >> 6;
  const int wr = wid >> 1;
  const int wc = wid & 1;

  u16* A_lds  = (u16*)smem;              // 16 KB, granule^(row&7)
  u16* B1_lds = (u16*)(smem + 16384);    // 8 KB (blob order)
  u16* B3_lds = (u16*)(smem + 24576);    // 8 KB

  const u16* a_src[4];
#pragma unroll
  for (int i = 0; i < 4; ++i) {
    int row = (wid * 4 + i) * 8 + (lane >> 3);
    int mg = mt * BM + row;
    int mc = (mg < cnt) ? mg : (cnt - 1);
    int tok = token_list[off + mc];
    a_src[i] = Xb + (size_t)tok * HDIM + (((lane & 7) ^ (row & 7)) * 8);
  }
  const u16* b1_src[2];
  const u16* b3_src[2];
  {
    size_t tbase = ((size_t)(e * 16 + nt) * 32) * TILE_E;
#pragma unroll
    for (int i = 0; i < 2; ++i) {
      int c = wid * 2 + i;
      b1_src[i] = w1b + tbase + c * 512 + lane * 8;
      b3_src[i] = w3b + tbase + c * 512 + lane * 8;
    }
  }

  f32x16 accg[2] = {};
  f32x16 accu[2] = {};

#pragma unroll
  for (int i = 0; i < 4; ++i) glds16(a_src[i], &A_lds[(wid * 4 + i) * 512]);
#pragma unroll
  for (int i = 0; i < 2; ++i) {
    glds16(b1_src[i], &B1_lds[(wid * 2 + i) * 512]);
    glds16(b3_src[i], &B3_lds[(wid * 2 + i) * 512]);
  }

#pragma unroll 1
  for (int t = 0; t < NK1; ++t) {
    __syncthreads();
    bf16x8 af[2][4], bg[4], bu[4];
#pragma unroll
    for (int m = 0; m < 2; ++m) {
      int R = wr * 64 + m * 32 + (lane & 31);
#pragma unroll
      for (int kk = 0; kk < 4; ++kk) {
        int gl = kk * 2 + (lane >> 5);
        af[m][kk] = *(const bf16x8*)&A_lds[R * BK + ((gl ^ (R & 7)) * 8)];
      }
    }
    {
      int R = wc * 32 + (lane & 31);
      int base = R * 16 + (((lane >> 5) ^ ((R >> 2) & 1)) * 8);
#pragma unroll
      for (int kk = 0; kk < 4; ++kk) {
        bg[kk] = *(const bf16x8*)&B1_lds[base + kk * 1024];
        bu[kk] = *(const bf16x8*)&B3_lds[base + kk * 1024];
      }
    }
    __syncthreads();
    if (t + 1 < NK1) {
      const size_t ks = (size_t)(t + 1) * BK;
      const size_t kb = (size_t)(t + 1) * TILE_E;
#pragma unroll
      for (int i = 0; i < 4; ++i) glds16(a_src[i] + ks, &A_lds[(wid * 4 + i) * 512]);
#pragma unroll
      for (int i = 0; i < 2; ++i) {
        glds16(b1_src[i] + kb, &B1_lds[(wid * 2 + i) * 512]);
        glds16(b3_src[i] + kb, &B3_lds[(wid * 2 + i) * 512]);
      }
    }
#pragma unroll
    for (int m = 0; m < 2; ++m)
#pragma unroll
      for (int kk = 0; kk < 4; ++kk) {
        accg[m] = __builtin_amdgcn_mfma_f32_32x32x16_bf16(af[m][kk], bg[kk], accg[m], 0, 0, 0);
        accu[m] = __builtin_amdgcn_mfma_f32_32x32x16_bf16(af[m][kk], bu[kk], accu[m], 0, 0, 0);
      }
  }

  const int fcol = nt * BN1 + wc * 32 + (lane & 31);
#pragma unroll
  for (int m = 0; m < 2; ++m) {
    int base = mt * BM + wr * 64 + m * 32 + 4 * (lane >> 5);
#pragma unroll
    for (int reg = 0; reg < 16; ++reg) {
      int mg = base + (reg & 3) + 8 * (reg >> 2);
      if (mg < cnt) {
        int slot = off + mg;
        float wgt = slot_w[slot];
        float g = accg[m][reg];
        float u = accu[m][reg];
        float sv = g / (1.f + __expf(-g));
        act[(size_t)slot * FDIM + fcol] = f2bf(sv * u * wgt);
      }
    }
  }
}

// ---------------------------------------------------------------------------
// GEMM2: y[token,h] += act[slot,:] @ w2 (blob). BM=128 BN=128 BK=64,
// wave tile 64x64. Proven schedule; new B-frag formula.
// ---------------------------------------------------------------------------
__global__ __launch_bounds__(NTHR, 3)
void gemm2_kernel(const u16* __restrict__ act,
                  const u16* __restrict__ w2b,   // tiled [e][nt32][kt16][4096]
                  const int* __restrict__ token_list,
                  const int* __restrict__ counts,
                  const int* __restrict__ offsets,
                  float* __restrict__ y) {
  const int bid = blockIdx.x;
  const int e  = bid >> 8;
  const int mt = (bid >> 4) & 15;
  const int nt = bid & 15;
  const int cnt = counts[e];
  if (mt * BM >= cnt) return;
  const int off = offsets[e];
  const int tid  = threadIdx.x;
  const int lane = tid & 63;
  const int wid  = tid >> 6;
  const int wr = wid >> 1;
  const int wc = wid & 1;

  __shared__ u16 A_lds[BM * BK];     // 16 KB
  __shared__ u16 B_lds[BN2 * BK];    // 16 KB (two tiles of 4096)

  const u16* a_src[4];
  const u16* b_src[4];
#pragma unroll
  for (int i = 0; i < 4; ++i) {
    int row = (wid * 4 + i) * 8 + (lane >> 3);
    int mg = mt * BM + row;
    int mc = (mg < cnt) ? mg : (cnt - 1);
    a_src[i] = act + (size_t)(off + mc) * FDIM + (((lane & 7) ^ (row & 7)) * 8);
    int c = wid * 4 + i;
    size_t tbase = ((size_t)(e * 32 + nt * 2 + (c >> 3)) * 16) * TILE_E;
    b_src[i] = w2b + tbase + (c & 7) * 512 + lane * 8;
  }

  f32x16 acc[2][2] = {};

#pragma unroll
  for (int i = 0; i < 4; ++i) {
    glds16(a_src[i], &A_lds[(wid * 4 + i) * 512]);
    glds16(b_src[i], &B_lds[(wid * 4 + i) * 512]);
  }

#pragma unroll 1
  for (int t = 0; t < NK2; ++t) {
    __syncthreads();
    bf16x8 af[2][4], bb[2][4];
#pragma unroll
    for (int m = 0; m < 2; ++m) {
      int R = wr * 64 + m * 32 + (lane & 31);
#pragma unroll
      for (int kk = 0; kk < 4; ++kk) {
        int gl = kk * 2 + (lane >> 5);
        af[m][kk] = *(const bf16x8*)&A_lds[R * BK + ((gl ^ (R & 7)) * 8)];
      }
    }
#pragma unroll
    for (int n = 0; n < 2; ++n) {
      int R = wc * 64 + n * 32 + (lane & 31);
      int base = (R >> 6) * TILE_E + (R & 63) * 16 + (((lane >> 5) ^ ((R >> 2) & 1)) * 8);
#pragma unroll
      for (int kk = 0; kk < 4; ++kk)
        bb[n][kk] = *(const bf16x8*)&B_lds[base + kk * 1024];
    }
    __syncthreads();
    if (t + 1 < NK2) {
      const size_t ks = (size_t)(t + 1) * BK;
      const size_t kb = (size_t)(t + 1) * TILE_E;
#pragma unroll
      for (int i = 0; i < 4; ++i) {
        glds16(a_src[i] + ks, &A_lds[(wid * 4 + i) * 512]);
        glds16(b_src[i] + kb, &B_lds[(wid * 4 + i) * 512]);
      }
    }
#pragma unroll
    for (int kk = 0; kk < 4; ++kk)
#pragma unroll
      for (int m = 0; m < 2; ++m)
#pragma unroll
        for (int n = 0; n < 2; ++n)
          acc[m][n] = __builtin_amdgcn_mfma_f32_32x32x16_bf16(af[m][kk], bb[n][kk], acc[m][n], 0, 0, 0);
  }

#pragma unroll
  for (int m = 0; m < 2; ++m) {
    int base = mt * BM + wr * 64 + m * 32 + 4 * (lane >> 5);
#pragma unroll
    for (int reg = 0; reg < 16; ++reg) {
      int mg = base + (reg & 3) + 8 * (reg >> 2);
      if (mg < cnt) {
        int slot = off + mg;
        int tok = token_list[slot];
#pragma unroll
        for (int n = 0; n < 2; ++n) {
          int hcol = nt * BN2 + wc * 64 + n * 32 + (lane & 31);
          unsafeAtomicAdd(y + (size_t)tok * HDIM + hcol, acc[m][n][reg]);
        }
      }
    }
  }
}

// ---------------------------------------------------------------------------
extern "C" void kernel_launch(void* const* d_in, const int* in_sizes, int n_in,
                              void* d_out, int out_size, void* d_ws, size_t ws_size,
                              hipStream_t stream) {
  (void)in_sizes; (void)n_in; (void)out_size; (void)ws_size;
  const float* hs     = (const float*)d_in[0];
  const float* logits = (const float*)d_in[1];
  const float* w1     = (const float*)d_in[2];
  const float* w3     = (const float*)d_in[3];
  const float* w2     = (const float*)d_in[4];
  float* y = (float*)d_out;

  uint8_t* ws = (uint8_t*)d_ws;
  int*   token_list = (int*)(ws);
  float* slot_w     = (float*)(ws + (16 << 10));
  int*   counts     = (int*)(ws + (32 << 10));
  int*   offsets    = (int*)(ws + (32 << 10) + 128);
  int*   cursor     = (int*)(ws + (32 << 10) + 256);
  int*   tok_e      = (int*)(ws + (33 << 10));
  float* tok_w      = (float*)(ws + (42 << 10));
  const size_t MB = 1 << 20;
  u16*   Xb  = (u16*)(ws + (64 << 10));                 // 8 MB
  u16*   act = (u16*)(ws + (64 << 10) + 8 * MB);        // 8 MB
  u16*   w1b = (u16*)(ws + (64 << 10) + 16 * MB);       // 32 MB tiled
  u16*   w3b = (u16*)(ws + (64 << 10) + 48 * MB);       // 32 MB tiled
  u16*   w2b = (u16*)(ws + (64 << 10) + 80 * MB);       // 32 MB tiled

  hipMemsetAsync(counts, 0, NEXP * sizeof(int), stream);
  route1_kernel<<<T_TOK / 256, 256, 0, stream>>>(logits, tok_e, tok_w, counts);
  route2_kernel<<<1, 64, 0, stream>>>(counts, offsets, cursor);
  route3_kernel<<<T_TOK / 256, 256, 0, stream>>>(tok_e, tok_w, cursor, token_list, slot_w);
  mega1_kernel<<<2560, 256, 0, stream>>>(w1, w3, w1b, w3b,
                                         (const float4*)hs, (ushort4*)Xb, (float4*)y);
  mega2_kernel<<<3072, 256, 0, stream>>>(w2, w2b, Xb, w1b, w3b,
                                         token_list, slot_w, counts, offsets, act);
  gemm2_kernel<<<GRID2K, NTHR, 0, stream>>>(act, w2b, token_list, counts, offsets, y);
}